// Round 6
// baseline (158.950 us; speedup 1.0000x reference)
//
#include <hip/hip_runtime.h>
#include <hip/hip_bf16.h>

// Causal MHA forward, bf16-MFMA flash attention, round 6.
// Q:[B,L,H,E] K:[B,S,H,E] V:[B,S,H,D] fp32 -> O:[B,L,H,D] fp32.
// B=2, L=S=2048, H=16, E=D=64, scale=0.125 folded into Q (log2 domain).
//
// Round-6 = round-5 structure with a DETERMINISTIC split-K combine:
//  - r5's last-finisher (atomicAdd + flag + relaxed loads) raced across XCDs
//    (G16) and 2M fp32 atomics were slow. Now: chunk0 -> plain stores to d_ws,
//    chunk1 -> plain stores to d_out (unnormalized), l's to d_ws; a second
//    kernel combines O = (O + Oacc)/(l0+l1) for rows 1024..2047. No atomics,
//    no memset, no flags; kernel boundary is the coherence point.
//  - Kept from r5: 128q blocks / 32q per wave (halves fragment LDS traffic),
//    exact per-CU balance (every CU = 34 tiles, max walk 16) via split-K,
//    double-buffered K/V with ONE barrier per tile, fused fp32->bf16 staging,
//    XOR-swizzled LDS, fixed-cap softmax (p = exp2(s-16)).

#define B_DIM 2
#define L_DIM 2048
#define H_DIM 16
#define E_DIM 64
#define NEG_INF (-1e30f)
#define CAP   16.0f

typedef __attribute__((ext_vector_type(8))) short short8;
typedef __attribute__((ext_vector_type(4))) float ffrag;

static __device__ __forceinline__ short f2bf(float x) {
    __hip_bfloat16 h = __float2bfloat16(x);
    return *reinterpret_cast<short*>(&h);
}
static __device__ __forceinline__ unsigned pk2(float lo, float hi) {
    __hip_bfloat162 h = __float22bfloat162_rn(make_float2(lo, hi));
    return *reinterpret_cast<unsigned*>(&h);
}

// Per-(j,k4) schedule: strip (128q), first tile, tile count. Strips 0..7 whole
// (2s+2 tiles); strips 8..15 split into two chunks of s+1 tiles. Every
// j-triple sums to exactly 34 tiles; max walk 16.
static __device__ const unsigned char T_strip[8][3] = {
    {0,15,15},{1,13,7},{2,13,6},{3,10,14},{8,4,14},{8,5,12},{9,10,12},{9,11,11}};
static __device__ const unsigned char T_t0[8][3] = {
    {0,0,16},{0,0,0},{0,14,0},{0,0,0},{0,0,15},{9,0,0},{0,11,13},{10,0,12}};
static __device__ const unsigned char T_nt[8][3] = {
    {2,16,16},{4,14,16},{6,14,14},{8,11,15},{9,10,15},{9,12,13},{10,11,13},{10,12,12}};

__global__ __launch_bounds__(256, 3)
void attn_fused(const float* __restrict__ Q, const float* __restrict__ K,
                const float* __restrict__ V, float* __restrict__ O,
                float* __restrict__ Oacc, float* __restrict__ lacc) {
    const int lid = blockIdx.x;           // 0..767
    const int cu  = lid & 255;            // CU slot (dispatch heuristic)
    const int k4  = lid >> 8;             // 0..2 residency slot
    const int bh  = cu & 31;              // head: XCD x gets bh === x (mod 8)
    const int j   = cu >> 5;              // 0..7 triple id
    const int b = bh >> 4, h = bh & 15;

    const int s   = T_strip[j][k4];
    const int t0  = T_t0[j][k4];
    const int ntl = T_nt[j][k4];
    const int q0  = s * 128;

    const int tid  = threadIdx.x;
    const int wave = tid >> 6;
    const int lane = tid & 63;
    const int n16  = lane & 15;
    const int quad = lane >> 4;

    __shared__ short Kt[8192];            // K tiles [key][dim], 2 buffers, swizzled
    __shared__ short Vt[8192];            // V tiles [dim][key], 2 buffers, swizzled
    __shared__ short Pq[8192];            // P per (wave,g): 8 x 2KB, swizzled

    const float sc = 0.125f * 1.44269504088896340736f;  // scale * log2(e)

    // ---- Q fragments: 2 groups of 16 queries per wave ----
    short8 qf[2][2];
#pragma unroll
    for (int g = 0; g < 2; ++g) {
        const int gq = q0 + 32 * wave + 16 * g + n16;
        const float4* pq = (const float4*)(Q + (((size_t)b * L_DIM + gq) * H_DIM + h) * E_DIM);
#pragma unroll
        for (int kt = 0; kt < 2; ++kt) {
            float4 x0 = pq[kt * 8 + quad * 2];
            float4 x1 = pq[kt * 8 + quad * 2 + 1];
            short8 f;
            f[0] = f2bf(x0.x * sc); f[1] = f2bf(x0.y * sc);
            f[2] = f2bf(x0.z * sc); f[3] = f2bf(x0.w * sc);
            f[4] = f2bf(x1.x * sc); f[5] = f2bf(x1.y * sc);
            f[6] = f2bf(x1.z * sc); f[7] = f2bf(x1.w * sc);
            qf[g][kt] = f;
        }
    }

    // ---- staging geometry ----
    const int rr  = tid >> 2;             // K row 0..63
    const int c2  = tid & 3;              // K 16-float chunk
    const int kOff0 = rr * 64 + (((2 * c2)     ^ (rr & 7)) * 8);
    const int kOff1 = rr * 64 + (((2 * c2 + 1) ^ (rr & 7)) * 8);
    const int kp2 = (tid & 31) * 2;       // V key pair 0..62
    const int c8  = (tid >> 5) * 8;       // V dim base 0..56

    float4 kr[4], va[2], vb2[2];

    auto load_tile = [&](int t) {
        const int kt0 = t * 64;
        const float4* kg = (const float4*)(K + (((size_t)b * L_DIM + kt0 + rr) * H_DIM + h) * E_DIM + c2 * 16);
        kr[0] = kg[0]; kr[1] = kg[1]; kr[2] = kg[2]; kr[3] = kg[3];
        const float* vp = V + (((size_t)b * L_DIM + kt0 + kp2) * H_DIM + h) * E_DIM + c8;
        const float4* vga = (const float4*)vp;
        const float4* vgb = (const float4*)(vp + H_DIM * E_DIM);
        va[0]  = vga[0]; va[1]  = vga[1];
        vb2[0] = vgb[0]; vb2[1] = vgb[1];
    };
    auto store_tile = [&](int bo) {
        short8 w0, w1;
        w0[0] = f2bf(kr[0].x); w0[1] = f2bf(kr[0].y); w0[2] = f2bf(kr[0].z); w0[3] = f2bf(kr[0].w);
        w0[4] = f2bf(kr[1].x); w0[5] = f2bf(kr[1].y); w0[6] = f2bf(kr[1].z); w0[7] = f2bf(kr[1].w);
        w1[0] = f2bf(kr[2].x); w1[1] = f2bf(kr[2].y); w1[2] = f2bf(kr[2].z); w1[3] = f2bf(kr[2].w);
        w1[4] = f2bf(kr[3].x); w1[5] = f2bf(kr[3].y); w1[6] = f2bf(kr[3].z); w1[7] = f2bf(kr[3].w);
        *(short8*)&Kt[bo + kOff0] = w0;
        *(short8*)&Kt[bo + kOff1] = w1;
        const float* a0 = (const float*)va;
        const float* b0 = (const float*)vb2;
#pragma unroll
        for (int i2 = 0; i2 < 8; ++i2)
            *(unsigned*)&Vt[bo + (c8 + i2) * 64 + (((kp2 >> 3) ^ i2) * 8) + (kp2 & 7)] = pk2(a0[i2], b0[i2]);
    };

    ffrag Oa[2][4];
#pragma unroll
    for (int g = 0; g < 2; ++g)
#pragma unroll
        for (int nt = 0; nt < 4; ++nt) Oa[g][nt] = ffrag{0.f, 0.f, 0.f, 0.f};
    float l2[2] = {0.f, 0.f};

    const int sw  = n16 & 7;
    const int fo0 = (quad ^ sw) * 8;
    const int fo1 = fo0 ^ 32;

    // ---- pipeline: 1 barrier/tile, double-buffered K/V ----
    load_tile(t0);
    store_tile(0);
    load_tile(t0 + 1);                    // ntl >= 2 always
    __syncthreads();

    for (int i = 0; i < ntl; ++i) {
        const int kt0 = (t0 + i) * 64;
        const int bo  = (i & 1) ? 4096 : 0;

        // S^T = K.Q^T
        ffrag S[2][4];
#pragma unroll
        for (int mt = 0; mt < 4; ++mt) {
            const int rb = bo + (mt * 16 + n16) * 64;
            short8 a0 = *(const short8*)&Kt[rb + fo0];
            short8 a1 = *(const short8*)&Kt[rb + fo1];
#pragma unroll
            for (int g = 0; g < 2; ++g) {
                ffrag z = ffrag{0.f, 0.f, 0.f, 0.f};
                z = __builtin_amdgcn_mfma_f32_16x16x32_bf16(a0, qf[g][0], z, 0, 0, 0);
                S[g][mt] = __builtin_amdgcn_mfma_f32_16x16x32_bf16(a1, qf[g][1], z, 0, 0, 0);
            }
        }

        // fixed-cap softmax + P -> LDS
#pragma unroll
        for (int g = 0; g < 2; ++g) {
            const int qmin = q0 + 32 * wave + 16 * g;
            const bool domask = (kt0 + 63 > qmin);
            short* pb = &Pq[(wave * 2 + g) * 1024 + n16 * 64];
            float ps = 0.f;
#pragma unroll
            for (int mt = 0; mt < 4; ++mt) {
                float pv[4];
#pragma unroll
                for (int r = 0; r < 4; ++r) {
                    float sv = S[g][mt][r];
                    if (domask && (kt0 + mt * 16 + quad * 4 + r > qmin + n16)) sv = NEG_INF;
                    pv[r] = exp2f(sv - CAP);
                    ps += pv[r];
                }
                uint2 w;
                w.x = pk2(pv[0], pv[1]);
                w.y = pk2(pv[2], pv[3]);
                *(uint2*)&pb[(((2 * mt + (quad >> 1)) ^ sw) * 8) + (quad & 1) * 4] = w;
            }
            ps += __shfl_xor(ps, 16);
            ps += __shfl_xor(ps, 32);
            l2[g] += ps;
        }

        short8 pa[2][2];
#pragma unroll
        for (int g = 0; g < 2; ++g) {
            const short* pb = &Pq[(wave * 2 + g) * 1024 + n16 * 64];
            pa[g][0] = *(const short8*)&pb[fo0];
            pa[g][1] = *(const short8*)&pb[fo1];
        }

        // O += P.V
#pragma unroll
        for (int nt = 0; nt < 4; ++nt) {
            const int rb = bo + (nt * 16 + n16) * 64;
            short8 b0 = *(const short8*)&Vt[rb + fo0];
            short8 b1 = *(const short8*)&Vt[rb + fo1];
#pragma unroll
            for (int g = 0; g < 2; ++g) {
                Oa[g][nt] = __builtin_amdgcn_mfma_f32_16x16x32_bf16(pa[g][0], b0, Oa[g][nt], 0, 0, 0);
                Oa[g][nt] = __builtin_amdgcn_mfma_f32_16x16x32_bf16(pa[g][1], b1, Oa[g][nt], 0, 0, 0);
            }
        }

        if (i + 1 < ntl) store_tile((i & 1) ? 0 : 4096);
        if (i + 2 < ntl) load_tile(t0 + i + 2);
        __syncthreads();
    }

    // ---- epilogue ----
    if (s < 8) {                          // whole strip: normalize + write direct
#pragma unroll
        for (int g = 0; g < 2; ++g)
#pragma unroll
            for (int r = 0; r < 4; ++r) {
                float li  = __shfl(l2[g], quad * 4 + r);
                float inv = 1.0f / li;
                const int row = q0 + 32 * wave + 16 * g + quad * 4 + r;
                float* op = O + (((size_t)b * L_DIM + row) * H_DIM + h) * E_DIM;
#pragma unroll
                for (int nt = 0; nt < 4; ++nt) op[nt * 16 + n16] = Oa[g][nt][r] * inv;
            }
        return;
    }

    // split chunk: plain-store partials; combine kernel merges afterwards.
    const int accIdx = bh * 8 + (s - 8);  // 0..255
    const int chunk  = (t0 != 0);         // 0 = first half, 1 = second half
    float* la = lacc + accIdx * 256 + chunk * 128;
#pragma unroll
    for (int g = 0; g < 2; ++g)
        if (quad == 0) la[32 * wave + 16 * g + n16] = l2[g];

    if (chunk == 0) {                     // partial -> workspace
        float* oa = Oacc + (size_t)accIdx * 8192;
#pragma unroll
        for (int g = 0; g < 2; ++g)
#pragma unroll
            for (int nt = 0; nt < 4; ++nt)
#pragma unroll
                for (int r = 0; r < 4; ++r)
                    oa[(32 * wave + 16 * g + quad * 4 + r) * 64 + nt * 16 + n16] = Oa[g][nt][r];
    } else {                              // partial -> d_out (unnormalized)
#pragma unroll
        for (int g = 0; g < 2; ++g)
#pragma unroll
            for (int r = 0; r < 4; ++r) {
                const int row = q0 + 32 * wave + 16 * g + quad * 4 + r;
                float* op = O + (((size_t)b * L_DIM + row) * H_DIM + h) * E_DIM;
#pragma unroll
                for (int nt = 0; nt < 4; ++nt) op[nt * 16 + n16] = Oa[g][nt][r];
            }
    }
}

// ---- combine: O = (O + Oacc) / (l0 + l1) for split strips (rows 1024+) ----
__global__ __launch_bounds__(256)
void combine(float* __restrict__ O, const float* __restrict__ Oacc,
             const float* __restrict__ lacc) {
    const int a  = blockIdx.x;            // accIdx 0..255
    const int bh = a >> 3;
    const int s  = 8 + (a & 7);
    const int b = bh >> 4, h = bh & 15;
    const int t = threadIdx.x;
    const int row = t >> 1;               // 0..127
    const int d0  = (t & 1) * 32;

    float l   = lacc[a * 256 + row] + lacc[a * 256 + 128 + row];
    float inv = 1.0f / l;
    const float4* pa = (const float4*)(Oacc + (size_t)a * 8192 + row * 64 + d0);
    float4* po = (float4*)(O + (((size_t)b * L_DIM + s * 128 + row) * H_DIM + h) * E_DIM + d0);
#pragma unroll
    for (int i = 0; i < 8; ++i) {
        float4 x = po[i], y = pa[i];
        po[i] = make_float4((x.x + y.x) * inv, (x.y + y.y) * inv,
                            (x.z + y.z) * inv, (x.w + y.w) * inv);
    }
}

extern "C" void kernel_launch(void* const* d_in, const int* in_sizes, int n_in,
                              void* d_out, int out_size, void* d_ws, size_t ws_size,
                              hipStream_t stream) {
    const float* Q = (const float*)d_in[0];
    const float* K = (const float*)d_in[1];
    const float* V = (const float*)d_in[2];
    float* O = (float*)d_out;
    float* Oacc = (float*)d_ws;                              // 256*8192*4 = 8,388,608 B
    float* lacc = (float*)((char*)d_ws + 8388608);           // 256*256*4  =   262,144 B
    // needs ws_size >= 8,650,752 B; no init required (all read slots are written)
    attn_fused<<<dim3(768), 256, 0, stream>>>(Q, K, V, O, Oacc, lacc);
    combine<<<dim3(256), 256, 0, stream>>>(O, Oacc, lacc);
}

// Round 7
// 144.124 us; speedup vs baseline: 1.1029x; 1.1029x over previous
//
#include <hip/hip_runtime.h>
#include <hip/hip_bf16.h>

// Causal MHA forward, bf16-MFMA flash attention, round 7.
// Q:[B,L,H,E] K:[B,S,H,E] V:[B,S,H,D] fp32 -> O:[B,L,H,D] fp32.
// B=2, L=S=2048, H=16, E=D=64, scale=0.125 folded into Q (log2 domain).
//
// r4->r6 lesson: halving all per-tile overheads didn't move the ~80 us wall;
// time = issue-work x ~5x latency-stall multiplier at ~7 effective waves/CU.
// Round 7 attacks occupancy:
//  1. VGPR <= 64 (launch_bounds(256,8) -> 32-waves/CU tier): no reg-prefetch,
//     single K/V LDS buffer (2 barriers/tile), per-mt fused softmax so S dies
//     immediately, packed bf16 cvts.
//  2. LDS 32 KB -> 5 blocks/CU; grid = 1280 uniform chunks (<=8 tiles) with a
//     static table making every CU-residue's 5 chunks sum to EXACTLY 34 tiles;
//     whole grid co-resident (5*256=1280) -> no dispatch tail.
//  3. l cross-quad reduction deferred to epilogue (no per-tile ds_swizzle).
//     Split chunks write bf16 partials + l to ws; combine kernel merges
//     (deterministic, no atomics). ws use: 13.6 MB.

#define B_DIM 2
#define L_DIM 2048
#define H_DIM 16
#define E_DIM 64
#define NEG_INF (-1e30f)
#define CAP   16.0f

typedef __attribute__((ext_vector_type(8))) short short8;
typedef __attribute__((ext_vector_type(4))) float ffrag;

static __device__ __forceinline__ short f2bf(float x) {
    __hip_bfloat16 h = __float2bfloat16(x);
    return *reinterpret_cast<short*>(&h);
}
static __device__ __forceinline__ unsigned pk2(float lo, float hi) {
    __hip_bfloat162 h = __float22bfloat162_rn(make_float2(lo, hi));
    return *reinterpret_cast<unsigned*>(&h);
}
static __device__ __forceinline__ float bf2f(unsigned u) {
    u <<= 16;
    return *reinterpret_cast<float*>(&u);
}
union U16 { uint4 u4; short8 s8; };

// Chunk schedule: c = r + 8k (k=0..4, r=0..7). Every r-class sums to 34 tiles.
// Strips s (128 queries), chunk [t0, t0+nt) of the 2s+2 causal 64-key tiles.
static __device__ const unsigned char Ts[5][8] = {
    {15,14,13,12,11,15,14,13},
    {12,11,10, 9, 8,15,14,13},
    {12,11,10, 9, 8,15, 7, 7},
    { 6, 5, 4, 3, 6,10,14, 2},
    { 0, 4, 8,12, 5, 9,13, 1}};
static __device__ const unsigned char Tt0[5][8] = {
    {24,16,16,16,16,16, 8, 8},
    { 8, 8, 8, 8, 8, 8, 0, 0},
    { 0, 0, 0, 0, 0, 0, 8, 0},
    { 0, 0, 0, 0, 8,16,24, 0},
    { 0, 8,16,24, 8,16,24, 0}};
static __device__ const unsigned char Tnt[5][8] = {
    {8,8,8,8,8,8,8,8},
    {8,8,8,8,8,8,8,8},
    {8,8,8,8,8,8,8,8},
    {8,8,8,8,6,6,6,6},
    {2,2,2,2,4,4,4,4}};

__global__ __launch_bounds__(256, 8)
void attn_fused(const float* __restrict__ Q, const float* __restrict__ K,
                const float* __restrict__ V, float* __restrict__ O,
                unsigned short* __restrict__ Opart, float* __restrict__ lacc) {
    const int lid = blockIdx.x;           // 0..1279
    const int bh  = lid & 31;             // head (XCD = bh%8 under lid%8 heuristic)
    const int c   = lid >> 5;             // chunk slot 0..39
    const int kk  = c >> 3, r = c & 7;
    const int s   = Ts[kk][r];
    const int t0  = Tt0[kk][r];
    const int ntl = Tnt[kk][r];
    const int q0  = s << 7;
    const int b = bh >> 4, h = bh & 15;
    const bool isfinal = (t0 + ntl == 2 * s + 2);

    const int tid  = threadIdx.x;
    const int wave = tid >> 6;
    const int lane = tid & 63;
    const int n16  = lane & 15;
    const int quad = lane >> 4;

    __shared__ short Kt[4096];            // K tile [key][dim], swizzled (8 KB)
    __shared__ short Vt[4096];            // V tile [dim][key], swizzled (8 KB)
    __shared__ short Pq[8192];            // P per (wave,g), swizzled (16 KB)

    const float sc = 0.125f * 1.44269504088896340736f;  // scale * log2(e)

    // ---- Q fragments: 2 groups of 16 queries per wave ----
    short8 qf[2][2];
#pragma unroll
    for (int g = 0; g < 2; ++g) {
        const int gq = q0 + 32 * wave + 16 * g + n16;
        const float4* pq = (const float4*)(Q + (((size_t)b * L_DIM + gq) * H_DIM + h) * E_DIM);
#pragma unroll
        for (int kt = 0; kt < 2; ++kt) {
            float4 x0 = pq[kt * 8 + quad * 2];
            float4 x1 = pq[kt * 8 + quad * 2 + 1];
            U16 u;
            u.u4.x = pk2(x0.x * sc, x0.y * sc);
            u.u4.y = pk2(x0.z * sc, x0.w * sc);
            u.u4.z = pk2(x1.x * sc, x1.y * sc);
            u.u4.w = pk2(x1.z * sc, x1.w * sc);
            qf[g][kt] = u.s8;
        }
    }

    // ---- staging geometry (XOR-swizzled, as r6) ----
    const int rr  = tid >> 2;             // K row 0..63
    const int c2  = tid & 3;              // K 16-float chunk
    const int kOff0 = rr * 64 + (((2 * c2)     ^ (rr & 7)) * 8);
    const int kOff1 = rr * 64 + (((2 * c2 + 1) ^ (rr & 7)) * 8);
    const int kp2 = (tid & 31) * 2;       // V key pair 0..62
    const int c8  = (tid >> 5) * 8;       // V dim base 0..56

    ffrag Oa[2][4];
#pragma unroll
    for (int g = 0; g < 2; ++g)
#pragma unroll
        for (int nt = 0; nt < 4; ++nt) Oa[g][nt] = ffrag{0.f, 0.f, 0.f, 0.f};
    float l2[2] = {0.f, 0.f};

    const int sw  = n16 & 7;
    const int fo0 = (quad ^ sw) * 8;
    const int fo1 = fo0 ^ 32;
    short* pb0 = &Pq[(wave * 2 + 0) * 1024 + n16 * 64];
    short* pb1 = &Pq[(wave * 2 + 1) * 1024 + n16 * 64];
    const int qrow0 = q0 + 32 * wave + n16;   // g0 row; g1 = +16

    for (int i = 0; i < ntl; ++i) {
        const int kt0 = (t0 + i) << 6;
        __syncthreads();                  // previous tile fully consumed
        {   // ---- stage K ----
            const float4* kg = (const float4*)(K + (((size_t)b * L_DIM + kt0 + rr) * H_DIM + h) * E_DIM + c2 * 16);
            float4 f0 = kg[0], f1 = kg[1];
            U16 u0;
            u0.u4.x = pk2(f0.x, f0.y); u0.u4.y = pk2(f0.z, f0.w);
            u0.u4.z = pk2(f1.x, f1.y); u0.u4.w = pk2(f1.z, f1.w);
            *(uint4*)&Kt[kOff0] = u0.u4;
            float4 f2 = kg[2], f3 = kg[3];
            U16 u1;
            u1.u4.x = pk2(f2.x, f2.y); u1.u4.y = pk2(f2.z, f2.w);
            u1.u4.z = pk2(f3.x, f3.y); u1.u4.w = pk2(f3.z, f3.w);
            *(uint4*)&Kt[kOff1] = u1.u4;
        }
        {   // ---- stage V (transposed, key-pairs packed) ----
            const float* vp = V + (((size_t)b * L_DIM + kt0 + kp2) * H_DIM + h) * E_DIM + c8;
            const float4* va4 = (const float4*)vp;
            const float4* vb4 = (const float4*)(vp + H_DIM * E_DIM);
            float4 a0 = va4[0], b0 = vb4[0];
            *(unsigned*)&Vt[(c8 + 0) * 64 + (((kp2 >> 3) ^ 0) * 8) + (kp2 & 7)] = pk2(a0.x, b0.x);
            *(unsigned*)&Vt[(c8 + 1) * 64 + (((kp2 >> 3) ^ 1) * 8) + (kp2 & 7)] = pk2(a0.y, b0.y);
            *(unsigned*)&Vt[(c8 + 2) * 64 + (((kp2 >> 3) ^ 2) * 8) + (kp2 & 7)] = pk2(a0.z, b0.z);
            *(unsigned*)&Vt[(c8 + 3) * 64 + (((kp2 >> 3) ^ 3) * 8) + (kp2 & 7)] = pk2(a0.w, b0.w);
            float4 a1 = va4[1], b1 = vb4[1];
            *(unsigned*)&Vt[(c8 + 4) * 64 + (((kp2 >> 3) ^ 4) * 8) + (kp2 & 7)] = pk2(a1.x, b1.x);
            *(unsigned*)&Vt[(c8 + 5) * 64 + (((kp2 >> 3) ^ 5) * 8) + (kp2 & 7)] = pk2(a1.y, b1.y);
            *(unsigned*)&Vt[(c8 + 6) * 64 + (((kp2 >> 3) ^ 6) * 8) + (kp2 & 7)] = pk2(a1.z, b1.z);
            *(unsigned*)&Vt[(c8 + 7) * 64 + (((kp2 >> 3) ^ 7) * 8) + (kp2 & 7)] = pk2(a1.w, b1.w);
        }
        __syncthreads();

        // ---- QK + per-mt fused softmax (S dies immediately; low VGPR) ----
        const bool diag = (kt0 + 64 > q0);   // wave-uniform: only diagonal chunk tiles
#pragma unroll
        for (int mt = 0; mt < 4; ++mt) {
            const int rb = (mt * 16 + n16) * 64;
            short8 a0 = *(const short8*)&Kt[rb + fo0];
            short8 a1 = *(const short8*)&Kt[rb + fo1];
            ffrag z0 = ffrag{0.f, 0.f, 0.f, 0.f};
            z0 = __builtin_amdgcn_mfma_f32_16x16x32_bf16(a0, qf[0][0], z0, 0, 0, 0);
            z0 = __builtin_amdgcn_mfma_f32_16x16x32_bf16(a1, qf[0][1], z0, 0, 0, 0);
            ffrag z1 = ffrag{0.f, 0.f, 0.f, 0.f};
            z1 = __builtin_amdgcn_mfma_f32_16x16x32_bf16(a0, qf[1][0], z1, 0, 0, 0);
            z1 = __builtin_amdgcn_mfma_f32_16x16x32_bf16(a1, qf[1][1], z1, 0, 0, 0);
            const int key0 = kt0 + mt * 16 + quad * 4;
            float pv0[4], pv1[4];
#pragma unroll
            for (int q = 0; q < 4; ++q) {
                float s0 = z0[q], s1 = z1[q];
                if (diag) {
                    if (key0 + q > qrow0)      s0 = NEG_INF;
                    if (key0 + q > qrow0 + 16) s1 = NEG_INF;
                }
                pv0[q] = exp2f(s0 - CAP);
                pv1[q] = exp2f(s1 - CAP);
                l2[0] += pv0[q];
                l2[1] += pv1[q];
            }
            const int poff = (((2 * mt + (quad >> 1)) ^ sw) * 8) + (quad & 1) * 4;
            uint2 w0, w1;
            w0.x = pk2(pv0[0], pv0[1]); w0.y = pk2(pv0[2], pv0[3]);
            w1.x = pk2(pv1[0], pv1[1]); w1.y = pk2(pv1[2], pv1[3]);
            *(uint2*)&pb0[poff] = w0;
            *(uint2*)&pb1[poff] = w1;
        }

        short8 p00 = *(const short8*)&pb0[fo0];
        short8 p01 = *(const short8*)&pb0[fo1];
        short8 p10 = *(const short8*)&pb1[fo0];
        short8 p11 = *(const short8*)&pb1[fo1];

        // ---- O += P.V ----
#pragma unroll
        for (int nt = 0; nt < 4; ++nt) {
            const int rb = (nt * 16 + n16) * 64;
            short8 v0 = *(const short8*)&Vt[rb + fo0];
            short8 v1 = *(const short8*)&Vt[rb + fo1];
            Oa[0][nt] = __builtin_amdgcn_mfma_f32_16x16x32_bf16(p00, v0, Oa[0][nt], 0, 0, 0);
            Oa[0][nt] = __builtin_amdgcn_mfma_f32_16x16x32_bf16(p01, v1, Oa[0][nt], 0, 0, 0);
            Oa[1][nt] = __builtin_amdgcn_mfma_f32_16x16x32_bf16(p10, v0, Oa[1][nt], 0, 0, 0);
            Oa[1][nt] = __builtin_amdgcn_mfma_f32_16x16x32_bf16(p11, v1, Oa[1][nt], 0, 0, 0);
        }
    }

    // ---- epilogue: cross-quad l reduction (deferred from the loop) ----
    float lf[2];
#pragma unroll
    for (int g = 0; g < 2; ++g) {
        float t = l2[g] + __shfl_xor(l2[g], 16);
        lf[g] = t + __shfl_xor(t, 32);
    }

    if (isfinal && t0 == 0) {             // single-chunk strip: normalize + write
#pragma unroll
        for (int g = 0; g < 2; ++g)
#pragma unroll
            for (int q = 0; q < 4; ++q) {
                float li  = __shfl(lf[g], quad * 4 + q);
                float inv = 1.0f / li;
                const int row = q0 + 32 * wave + 16 * g + quad * 4 + q;
                float* op = O + (((size_t)b * L_DIM + row) * H_DIM + h) * E_DIM;
#pragma unroll
                for (int nt = 0; nt < 4; ++nt) op[nt * 16 + n16] = Oa[g][nt][q] * inv;
            }
        return;
    }

    // multi-chunk strip: store l for this chunk
    const int pos = t0 >> 3;
    if (quad == 0) {
#pragma unroll
        for (int g = 0; g < 2; ++g)
            lacc[((bh * 16 + s) * 4 + pos) * 128 + 32 * wave + 16 * g + n16] = lf[g];
    }

    if (isfinal) {                        // final chunk: raw fp32 into d_out
#pragma unroll
        for (int g = 0; g < 2; ++g)
#pragma unroll
            for (int q = 0; q < 4; ++q) {
                const int row = q0 + 32 * wave + 16 * g + quad * 4 + q;
                float* op = O + (((size_t)b * L_DIM + row) * H_DIM + h) * E_DIM;
#pragma unroll
                for (int nt = 0; nt < 4; ++nt) op[nt * 16 + n16] = Oa[g][nt][q];
            }
    } else {                              // non-final: bf16 partial into ws
        const int base = (s < 8) ? (s - 4) : ((s < 12) ? 4 + 2 * (s - 8) : 12 + 3 * (s - 12));
        unsigned short* op = Opart + (size_t)(bh * 24 + base + pos) * 8192;
#pragma unroll
        for (int g = 0; g < 2; ++g)
#pragma unroll
            for (int q = 0; q < 4; ++q) {
                const int rl = 32 * wave + 16 * g + quad * 4 + q;
#pragma unroll
                for (int nt = 0; nt < 4; ++nt)
                    op[rl * 64 + nt * 16 + n16] = (unsigned short)f2bf(Oa[g][nt][q]);
            }
    }
}

// ---- combine: O = (O + sum bf16 partials) / sum l, strips s>=4 ----
__global__ __launch_bounds__(256)
void combine(float* __restrict__ O, const unsigned short* __restrict__ Opart,
             const float* __restrict__ lacc) {
    const int a    = blockIdx.x;          // 0..383
    const int head = a & 31;
    const int s    = 4 + (a >> 5);
    const int b = head >> 4, h = head & 15;
    const int npos = (s < 8) ? 2 : ((s < 12) ? 3 : 4);
    const int base = (s < 8) ? (s - 4) : ((s < 12) ? 4 + 2 * (s - 8) : 12 + 3 * (s - 12));
    const int t   = threadIdx.x;
    const int row = t >> 1;
    const int d0  = (t & 1) * 32;

    float l = 0.f;
    for (int pos = 0; pos < npos; ++pos)
        l += lacc[((head * 16 + s) * 4 + pos) * 128 + row];
    const float inv = 1.0f / l;

    float* po = O + (((size_t)b * L_DIM + s * 128 + row) * H_DIM + h) * E_DIM + d0;
    float acc[32];
#pragma unroll
    for (int i = 0; i < 8; ++i) {
        float4 x = ((const float4*)po)[i];
        acc[i * 4 + 0] = x.x; acc[i * 4 + 1] = x.y;
        acc[i * 4 + 2] = x.z; acc[i * 4 + 3] = x.w;
    }
    for (int pos = 0; pos + 1 < npos; ++pos) {
        const unsigned short* pp = Opart + (size_t)(head * 24 + base + pos) * 8192 + row * 64 + d0;
#pragma unroll
        for (int j = 0; j < 4; ++j) {
            uint4 w = ((const uint4*)pp)[j];
            acc[j * 8 + 0] += bf2f(w.x & 0xffffu); acc[j * 8 + 1] += bf2f(w.x >> 16);
            acc[j * 8 + 2] += bf2f(w.y & 0xffffu); acc[j * 8 + 3] += bf2f(w.y >> 16);
            acc[j * 8 + 4] += bf2f(w.z & 0xffffu); acc[j * 8 + 5] += bf2f(w.z >> 16);
            acc[j * 8 + 6] += bf2f(w.w & 0xffffu); acc[j * 8 + 7] += bf2f(w.w >> 16);
        }
    }
#pragma unroll
    for (int i = 0; i < 8; ++i)
        ((float4*)po)[i] = make_float4(acc[i * 4 + 0] * inv, acc[i * 4 + 1] * inv,
                                       acc[i * 4 + 2] * inv, acc[i * 4 + 3] * inv);
}

extern "C" void kernel_launch(void* const* d_in, const int* in_sizes, int n_in,
                              void* d_out, int out_size, void* d_ws, size_t ws_size,
                              hipStream_t stream) {
    const float* Q = (const float*)d_in[0];
    const float* K = (const float*)d_in[1];
    const float* V = (const float*)d_in[2];
    float* O = (float*)d_out;
    unsigned short* Opart = (unsigned short*)d_ws;              // 768*8192*2 = 12,582,912 B
    float* lacc = (float*)((char*)d_ws + 12582912);             // 2048*128*4 =  1,048,576 B
    // needs ws_size >= 13,631,488 B; no init needed (every read slot is written)
    attn_fused<<<dim3(1280), 256, 0, stream>>>(Q, K, V, O, Opart, lacc);
    combine<<<dim3(384), 256, 0, stream>>>(O, Opart, lacc);
}

// Round 8
// 142.324 us; speedup vs baseline: 1.1168x; 1.0126x over previous
//
#include <hip/hip_runtime.h>
#include <hip/hip_bf16.h>

// Causal MHA forward, bf16-MFMA flash attention, round 8.
// Q:[B,L,H,E] K:[B,S,H,E] V:[B,S,H,D] fp32 -> O:[B,L,H,D] fp32.
// B=2, L=S=2048, H=16, E=D=64, scale=0.125 folded into Q (log2 domain).
//
// r7 result: 65 us, VALUBusy 49%, MfmaUtil 11%, occ 30%. Measured VALU-busy
// (~32 us) is ~4x the source-level VALU work -> hip_bf16 header conversions
// are lowering to software RNE (~10 ops/cvt), ~32 cvt-pairs per wave-tile.
// Round-8 changes (structure identical to r7):
//  1. All bf16 packs via integer round-half-up: bits+0x8000 then ONE
//     v_perm_b32 per pair (3 VALU ops / 2 conversions, guaranteed).
//  2. CAP folded into MFMA C-init (scores start at -16) -> deletes 32 v_sub
//     per wave-tile.
//  3. V staged 4 keys x 4 dims per thread -> 4 ds_write_b64 (was 8 b32).

#define B_DIM 2
#define L_DIM 2048
#define H_DIM 16
#define E_DIM 64
#define NEG_INF (-1e30f)
#define CAP   16.0f

typedef __attribute__((ext_vector_type(8))) short short8;
typedef __attribute__((ext_vector_type(4))) float ffrag;

// bf16 pack, round-half-up: 2 v_add_u32 + 1 v_perm_b32.
static __device__ __forceinline__ unsigned pk2f(float lo, float hi) {
    unsigned a = __builtin_bit_cast(unsigned, lo) + 0x8000u;
    unsigned b = __builtin_bit_cast(unsigned, hi) + 0x8000u;
    return __builtin_amdgcn_perm(b, a, 0x07060302);  // {b.hi16, a.hi16}
}
static __device__ __forceinline__ unsigned short f2bf_r(float x) {
    return (unsigned short)((__builtin_bit_cast(unsigned, x) + 0x8000u) >> 16);
}
static __device__ __forceinline__ float bf2f(unsigned u) {
    u <<= 16;
    return __builtin_bit_cast(float, u);
}
union U16 { uint4 u4; short8 s8; };

// Chunk schedule: c = r + 8k (k=0..4, r=0..7). Every r-class sums to 34 tiles.
// Strips s (128 queries), chunk [t0, t0+nt) of the 2s+2 causal 64-key tiles.
static __device__ const unsigned char Ts[5][8] = {
    {15,14,13,12,11,15,14,13},
    {12,11,10, 9, 8,15,14,13},
    {12,11,10, 9, 8,15, 7, 7},
    { 6, 5, 4, 3, 6,10,14, 2},
    { 0, 4, 8,12, 5, 9,13, 1}};
static __device__ const unsigned char Tt0[5][8] = {
    {24,16,16,16,16,16, 8, 8},
    { 8, 8, 8, 8, 8, 8, 0, 0},
    { 0, 0, 0, 0, 0, 0, 8, 0},
    { 0, 0, 0, 0, 8,16,24, 0},
    { 0, 8,16,24, 8,16,24, 0}};
static __device__ const unsigned char Tnt[5][8] = {
    {8,8,8,8,8,8,8,8},
    {8,8,8,8,8,8,8,8},
    {8,8,8,8,8,8,8,8},
    {8,8,8,8,6,6,6,6},
    {2,2,2,2,4,4,4,4}};

__global__ __launch_bounds__(256, 8)
void attn_fused(const float* __restrict__ Q, const float* __restrict__ K,
                const float* __restrict__ V, float* __restrict__ O,
                unsigned short* __restrict__ Opart, float* __restrict__ lacc) {
    const int lid = blockIdx.x;           // 0..1279
    const int bh  = lid & 31;             // head (XCD = bh%8 under lid%8 heuristic)
    const int c   = lid >> 5;             // chunk slot 0..39
    const int kk  = c >> 3, r = c & 7;
    const int s   = Ts[kk][r];
    const int t0  = Tt0[kk][r];
    const int ntl = Tnt[kk][r];
    const int q0  = s << 7;
    const int b = bh >> 4, h = bh & 15;
    const bool isfinal = (t0 + ntl == 2 * s + 2);

    const int tid  = threadIdx.x;
    const int wave = tid >> 6;
    const int lane = tid & 63;
    const int n16  = lane & 15;
    const int quad = lane >> 4;

    __shared__ short Kt[4096];            // K tile [key][dim], swizzled (8 KB)
    __shared__ short Vt[4096];            // V tile [dim][key], swizzled (8 KB)
    __shared__ short Pq[8192];            // P per (wave,g), swizzled (16 KB)

    const float sc = 0.125f * 1.44269504088896340736f;  // scale * log2(e)

    // ---- Q fragments: 2 groups of 16 queries per wave ----
    short8 qf[2][2];
#pragma unroll
    for (int g = 0; g < 2; ++g) {
        const int gq = q0 + 32 * wave + 16 * g + n16;
        const float4* pq = (const float4*)(Q + (((size_t)b * L_DIM + gq) * H_DIM + h) * E_DIM);
#pragma unroll
        for (int kt = 0; kt < 2; ++kt) {
            float4 x0 = pq[kt * 8 + quad * 2];
            float4 x1 = pq[kt * 8 + quad * 2 + 1];
            U16 u;
            u.u4.x = pk2f(x0.x * sc, x0.y * sc);
            u.u4.y = pk2f(x0.z * sc, x0.w * sc);
            u.u4.z = pk2f(x1.x * sc, x1.y * sc);
            u.u4.w = pk2f(x1.z * sc, x1.w * sc);
            qf[g][kt] = u.s8;
        }
    }

    // ---- staging geometry (XOR-swizzled) ----
    const int rr  = tid >> 2;             // K row 0..63
    const int c2  = tid & 3;              // K 16-float chunk
    const int kOff0 = rr * 64 + (((2 * c2)     ^ (rr & 7)) * 8);
    const int kOff1 = rr * 64 + (((2 * c2 + 1) ^ (rr & 7)) * 8);
    const int kq  = (tid & 15) * 4;       // V key base 0..60
    const int d4  = (tid >> 4) * 4;       // V dim base 0..60

    ffrag Oa[2][4];
#pragma unroll
    for (int g = 0; g < 2; ++g)
#pragma unroll
        for (int nt = 0; nt < 4; ++nt) Oa[g][nt] = ffrag{0.f, 0.f, 0.f, 0.f};
    float l2[2] = {0.f, 0.f};

    const int sw  = n16 & 7;
    const int fo0 = (quad ^ sw) * 8;
    const int fo1 = fo0 ^ 32;
    short* pb0 = &Pq[(wave * 2 + 0) * 1024 + n16 * 64];
    short* pb1 = &Pq[(wave * 2 + 1) * 1024 + n16 * 64];
    const int qrow0 = q0 + 32 * wave + n16;   // g0 row; g1 = +16

    for (int i = 0; i < ntl; ++i) {
        const int kt0 = (t0 + i) << 6;
        __syncthreads();                  // previous tile fully consumed
        {   // ---- stage K: row rr, dims c2*16..+16 ----
            const float4* kg = (const float4*)(K + (((size_t)b * L_DIM + kt0 + rr) * H_DIM + h) * E_DIM + c2 * 16);
            float4 f0 = kg[0], f1 = kg[1];
            U16 u0;
            u0.u4.x = pk2f(f0.x, f0.y); u0.u4.y = pk2f(f0.z, f0.w);
            u0.u4.z = pk2f(f1.x, f1.y); u0.u4.w = pk2f(f1.z, f1.w);
            *(uint4*)&Kt[kOff0] = u0.u4;
            float4 f2 = kg[2], f3 = kg[3];
            U16 u1;
            u1.u4.x = pk2f(f2.x, f2.y); u1.u4.y = pk2f(f2.z, f2.w);
            u1.u4.z = pk2f(f3.x, f3.y); u1.u4.w = pk2f(f3.z, f3.w);
            *(uint4*)&Kt[kOff1] = u1.u4;
        }
        {   // ---- stage V transposed: 4 keys x 4 dims -> 4 ds_write_b64 ----
            const float* vp = V + (((size_t)b * L_DIM + kt0 + kq) * H_DIM + h) * E_DIM + d4;
            float4 v0 = *(const float4*)(vp);
            float4 v1 = *(const float4*)(vp + 1024);
            float4 v2 = *(const float4*)(vp + 2048);
            float4 v3 = *(const float4*)(vp + 3072);
            const int kb = kq >> 3, ko = kq & 7;
#pragma unroll
            for (int i2 = 0; i2 < 4; ++i2) {
                const int d = d4 + i2;
                uint2 w;
                w.x = pk2f(((const float*)&v0)[i2], ((const float*)&v1)[i2]);
                w.y = pk2f(((const float*)&v2)[i2], ((const float*)&v3)[i2]);
                *(uint2*)&Vt[d * 64 + ((kb ^ (d & 7)) * 8) + ko] = w;
            }
        }
        __syncthreads();

        // ---- QK (C-init = -CAP) + fused softmax ----
        const bool diag = (kt0 + 64 > q0);   // wave-uniform
#pragma unroll
        for (int mt = 0; mt < 4; ++mt) {
            const int rb = (mt * 16 + n16) * 64;
            short8 a0 = *(const short8*)&Kt[rb + fo0];
            short8 a1 = *(const short8*)&Kt[rb + fo1];
            ffrag z0 = ffrag{-CAP, -CAP, -CAP, -CAP};
            z0 = __builtin_amdgcn_mfma_f32_16x16x32_bf16(a0, qf[0][0], z0, 0, 0, 0);
            z0 = __builtin_amdgcn_mfma_f32_16x16x32_bf16(a1, qf[0][1], z0, 0, 0, 0);
            ffrag z1 = ffrag{-CAP, -CAP, -CAP, -CAP};
            z1 = __builtin_amdgcn_mfma_f32_16x16x32_bf16(a0, qf[1][0], z1, 0, 0, 0);
            z1 = __builtin_amdgcn_mfma_f32_16x16x32_bf16(a1, qf[1][1], z1, 0, 0, 0);
            const int key0 = kt0 + mt * 16 + quad * 4;
            float pv0[4], pv1[4];
#pragma unroll
            for (int q = 0; q < 4; ++q) {
                float s0 = z0[q], s1 = z1[q];
                if (diag) {
                    if (key0 + q > qrow0)      s0 = NEG_INF;
                    if (key0 + q > qrow0 + 16) s1 = NEG_INF;
                }
                pv0[q] = exp2f(s0);
                pv1[q] = exp2f(s1);
                l2[0] += pv0[q];
                l2[1] += pv1[q];
            }
            const int poff = (((2 * mt + (quad >> 1)) ^ sw) * 8) + (quad & 1) * 4;
            uint2 w0, w1;
            w0.x = pk2f(pv0[0], pv0[1]); w0.y = pk2f(pv0[2], pv0[3]);
            w1.x = pk2f(pv1[0], pv1[1]); w1.y = pk2f(pv1[2], pv1[3]);
            *(uint2*)&pb0[poff] = w0;
            *(uint2*)&pb1[poff] = w1;
        }

        short8 p00 = *(const short8*)&pb0[fo0];
        short8 p01 = *(const short8*)&pb0[fo1];
        short8 p10 = *(const short8*)&pb1[fo0];
        short8 p11 = *(const short8*)&pb1[fo1];

        // ---- O += P.V ----
#pragma unroll
        for (int nt = 0; nt < 4; ++nt) {
            const int rb = (nt * 16 + n16) * 64;
            short8 v0 = *(const short8*)&Vt[rb + fo0];
            short8 v1 = *(const short8*)&Vt[rb + fo1];
            Oa[0][nt] = __builtin_amdgcn_mfma_f32_16x16x32_bf16(p00, v0, Oa[0][nt], 0, 0, 0);
            Oa[0][nt] = __builtin_amdgcn_mfma_f32_16x16x32_bf16(p01, v1, Oa[0][nt], 0, 0, 0);
            Oa[1][nt] = __builtin_amdgcn_mfma_f32_16x16x32_bf16(p10, v0, Oa[1][nt], 0, 0, 0);
            Oa[1][nt] = __builtin_amdgcn_mfma_f32_16x16x32_bf16(p11, v1, Oa[1][nt], 0, 0, 0);
        }
    }

    // ---- epilogue: cross-quad l reduction (deferred from the loop) ----
    float lf[2];
#pragma unroll
    for (int g = 0; g < 2; ++g) {
        float t = l2[g] + __shfl_xor(l2[g], 16);
        lf[g] = t + __shfl_xor(t, 32);
    }

    if (isfinal && t0 == 0) {             // single-chunk strip: normalize + write
#pragma unroll
        for (int g = 0; g < 2; ++g)
#pragma unroll
            for (int q = 0; q < 4; ++q) {
                float li  = __shfl(lf[g], quad * 4 + q);
                float inv = 1.0f / li;
                const int row = q0 + 32 * wave + 16 * g + quad * 4 + q;
                float* op = O + (((size_t)b * L_DIM + row) * H_DIM + h) * E_DIM;
#pragma unroll
                for (int nt = 0; nt < 4; ++nt) op[nt * 16 + n16] = Oa[g][nt][q] * inv;
            }
        return;
    }

    // multi-chunk strip: store l for this chunk
    const int pos = t0 >> 3;
    if (quad == 0) {
#pragma unroll
        for (int g = 0; g < 2; ++g)
            lacc[((bh * 16 + s) * 4 + pos) * 128 + 32 * wave + 16 * g + n16] = lf[g];
    }

    if (isfinal) {                        // final chunk: raw fp32 into d_out
#pragma unroll
        for (int g = 0; g < 2; ++g)
#pragma unroll
            for (int q = 0; q < 4; ++q) {
                const int row = q0 + 32 * wave + 16 * g + quad * 4 + q;
                float* op = O + (((size_t)b * L_DIM + row) * H_DIM + h) * E_DIM;
#pragma unroll
                for (int nt = 0; nt < 4; ++nt) op[nt * 16 + n16] = Oa[g][nt][q];
            }
    } else {                              // non-final: bf16 partial into ws
        const int base = (s < 8) ? (s - 4) : ((s < 12) ? 4 + 2 * (s - 8) : 12 + 3 * (s - 12));
        unsigned short* op = Opart + (size_t)(bh * 24 + base + pos) * 8192;
#pragma unroll
        for (int g = 0; g < 2; ++g)
#pragma unroll
            for (int q = 0; q < 4; ++q) {
                const int rl = 32 * wave + 16 * g + quad * 4 + q;
#pragma unroll
                for (int nt = 0; nt < 4; ++nt)
                    op[rl * 64 + nt * 16 + n16] = f2bf_r(Oa[g][nt][q]);
            }
    }
}

// ---- combine: O = (O + sum bf16 partials) / sum l, strips s>=4 ----
__global__ __launch_bounds__(256)
void combine(float* __restrict__ O, const unsigned short* __restrict__ Opart,
             const float* __restrict__ lacc) {
    const int a    = blockIdx.x;          // 0..383
    const int head = a & 31;
    const int s    = 4 + (a >> 5);
    const int b = head >> 4, h = head & 15;
    const int npos = (s < 8) ? 2 : ((s < 12) ? 3 : 4);
    const int base = (s < 8) ? (s - 4) : ((s < 12) ? 4 + 2 * (s - 8) : 12 + 3 * (s - 12));
    const int t   = threadIdx.x;
    const int row = t >> 1;
    const int d0  = (t & 1) * 32;

    float l = 0.f;
    for (int pos = 0; pos < npos; ++pos)
        l += lacc[((head * 16 + s) * 4 + pos) * 128 + row];
    const float inv = 1.0f / l;

    float* po = O + (((size_t)b * L_DIM + s * 128 + row) * H_DIM + h) * E_DIM + d0;
    float acc[32];
#pragma unroll
    for (int i = 0; i < 8; ++i) {
        float4 x = ((const float4*)po)[i];
        acc[i * 4 + 0] = x.x; acc[i * 4 + 1] = x.y;
        acc[i * 4 + 2] = x.z; acc[i * 4 + 3] = x.w;
    }
    for (int pos = 0; pos + 1 < npos; ++pos) {
        const unsigned short* pp = Opart + (size_t)(head * 24 + base + pos) * 8192 + row * 64 + d0;
#pragma unroll
        for (int j = 0; j < 4; ++j) {
            uint4 w = ((const uint4*)pp)[j];
            acc[j * 8 + 0] += bf2f(w.x & 0xffffu); acc[j * 8 + 1] += bf2f(w.x >> 16);
            acc[j * 8 + 2] += bf2f(w.y & 0xffffu); acc[j * 8 + 3] += bf2f(w.y >> 16);
            acc[j * 8 + 4] += bf2f(w.z & 0xffffu); acc[j * 8 + 5] += bf2f(w.z >> 16);
            acc[j * 8 + 6] += bf2f(w.w & 0xffffu); acc[j * 8 + 7] += bf2f(w.w >> 16);
        }
    }
#pragma unroll
    for (int i = 0; i < 8; ++i)
        ((float4*)po)[i] = make_float4(acc[i * 4 + 0] * inv, acc[i * 4 + 1] * inv,
                                       acc[i * 4 + 2] * inv, acc[i * 4 + 3] * inv);
}

extern "C" void kernel_launch(void* const* d_in, const int* in_sizes, int n_in,
                              void* d_out, int out_size, void* d_ws, size_t ws_size,
                              hipStream_t stream) {
    const float* Q = (const float*)d_in[0];
    const float* K = (const float*)d_in[1];
    const float* V = (const float*)d_in[2];
    float* O = (float*)d_out;
    unsigned short* Opart = (unsigned short*)d_ws;              // 768*8192*2 = 12,582,912 B
    float* lacc = (float*)((char*)d_ws + 12582912);             // 2048*128*4 =  1,048,576 B
    // needs ws_size >= 13,631,488 B; no init needed (every read slot is written)
    attn_fused<<<dim3(1280), 256, 0, stream>>>(Q, K, V, O, Opart, lacc);
    combine<<<dim3(384), 256, 0, stream>>>(O, Opart, lacc);
}